// Round 1
// baseline (26554.233 us; speedup 1.0000x reference)
//
#include <hip/hip_runtime.h>

// Seq2Seq LSTM forecaster: H=256, B=256, S=672, T=96.
// Design: weight-stationary tensor-parallel persistent kernels.
//   - 256 wgs = 16 batch-groups (16 batch rows each) x 16 channel-shards (16 H-channels each).
//   - Each wg keeps its [256 x 64] gate-weight slices as bf16 MFMA fragments in VGPRs.
//   - Per tick: 16x16x32 bf16 MFMAs -> f32 gates -> LSTM pointwise (f32 c-state in regs)
//     -> bf16 h slice written to L2 exchange buffer -> 16-wg device-scope barrier.
//   - Encoder layer-pipelined: tick t computes layer0 step t and layer1 step t-1 (1 barrier/tick).
//   - Decoder: 3 phases/step (layer0, layer1, head) with pred feedback via f32 atomics.
// Runtime dtype detection (f32 vs bf16 device buffers) via exponent-field statistic.

#define S_LEN 672
#define T_LEN 96
#define HDIM  256

typedef short short8 __attribute__((ext_vector_type(8)));
typedef float f32x4  __attribute__((ext_vector_type(4)));

// ---- workspace layout (bytes) ----
#define OFF_CTR1 0                      // 16 groups x 16 u32 (64B apart)
#define OFF_CTR2 1024
#define OFF_FLAG 2048                   // dtype mode flag
#define OFF_H0EX 4096                   // [16 g][2 parity][16 b][256 ch] bf16
#define OFF_H1EX (OFF_H0EX + 16*2*16*256*2)
#define OFF_PRED (OFF_H1EX + 16*2*16*256*2)   // [2][256] f32
#define ZERO_END (OFF_PRED + 2*256*4)
#define OFF_C0   ZERO_END               // [256][256] f32
#define OFF_C1   (OFF_C0 + 256*256*4)

__device__ __forceinline__ unsigned short f2bf(float f) {
  unsigned u = __float_as_uint(f);
  u += 0x7FFFu + ((u >> 16) & 1u);      // round-to-nearest-even
  return (unsigned short)(u >> 16);
}
__device__ __forceinline__ float bf2f(unsigned short s) {
  return __uint_as_float(((unsigned)s) << 16);
}
__device__ __forceinline__ float ld_scalar(const void* p, long idx, int mode) {
  if (mode) return bf2f(((const unsigned short*)p)[idx]);
  return ((const float*)p)[idx];
}
__device__ __forceinline__ short8 ld_frag8(const void* p, long row, long ld, long k0, int mode) {
  if (mode) {
    return *(const short8*)((const unsigned short*)p + row * ld + k0);
  } else {
    const float* f = (const float*)p + row * ld + k0;
    short8 r;
#pragma unroll
    for (int i = 0; i < 8; i++) r[i] = (short)f2bf(f[i]);
    return r;
  }
}
__device__ __forceinline__ void st_out(void* out, size_t idx, float v, int mode) {
  if (mode) ((unsigned short*)out)[idx] = f2bf(v);
  else      ((float*)out)[idx] = v;
}
__device__ __forceinline__ float sigm(float x) { return 1.f / (1.f + __expf(-x)); }

__device__ __forceinline__ f32x4 mfma_bf16(short8 a, short8 b, f32x4 c) {
  return __builtin_amdgcn_mfma_f32_16x16x32_bf16(a, b, c, 0, 0, 0);
}

// 16-wg group barrier: per-wave release add (drains the wave's stores), one spinner,
// acquire fence on exit so peers' h-writes are visible.
__device__ __forceinline__ void group_barrier(unsigned* ctr, unsigned expected) {
  __syncthreads();
  if ((threadIdx.x & 63) == 0)
    __hip_atomic_fetch_add(ctr, 1u, __ATOMIC_RELEASE, __HIP_MEMORY_SCOPE_AGENT);
  if (threadIdx.x == 0) {
    while (__hip_atomic_load(ctr, __ATOMIC_RELAXED, __HIP_MEMORY_SCOPE_AGENT) < expected)
      __builtin_amdgcn_s_sleep(1);
  }
  __syncthreads();
  __builtin_amdgcn_fence(__ATOMIC_ACQUIRE, "agent");
}

// ---- dtype detector: low-16-bit exponent-field statistic over features ----
// f32 N(0,1): low 16 bits are ~uniform mantissa bits -> ~12% hits.
// bf16-packed: low half is a bf16 sample -> exponent in [100,130] ~100% hits.
__global__ void detect_mode(const unsigned* __restrict__ feat, unsigned* __restrict__ flag) {
  const int t = threadIdx.x;
  int cnt = 0;
#pragma unroll
  for (int i = 0; i < 8; i++) {
    const unsigned wv = feat[t * 8 + i];
    const unsigned e = (wv >> 7) & 0xFFu;
    cnt += (e >= 100u && e <= 130u) ? 1 : 0;
  }
#pragma unroll
  for (int o = 32; o > 0; o >>= 1) cnt += __shfl_down(cnt, o, 64);
  if (t == 0) flag[0] = (cnt >= 256) ? 1u : 0u;
}

// ============================ encoder ============================
__global__ void __launch_bounds__(256, 1)
enc_kernel(const void* __restrict__ feat,
           const void* __restrict__ Wih0, const void* __restrict__ Whh0, const void* __restrict__ b0,
           const void* __restrict__ Wih1, const void* __restrict__ Whh1, const void* __restrict__ b1,
           char* __restrict__ ws) {
  const int mode = (int)*(const unsigned*)(ws + OFF_FLAG);
  const int tid  = threadIdx.x;
  const int lane = tid & 63;
  const int w    = tid >> 6;                 // wave 0..3
  const int bId  = blockIdx.x;
  const int g    = (bId & 7) * 2 + ((bId >> 3) & 1);   // group: same XCD-residue for all members
  const int m    = bId >> 4;                           // member 0..15 (channel shard)

  const int fcol = lane & 15;                // fragment row/col index
  const int kq   = lane >> 4;                // k-quarter
  const int pb   = lane & 15;                // pointwise: local batch
  const int pcl  = lane >> 4;                // pointwise: 0..3
  const int ch   = m * 16 + w * 4 + pcl;     // global channel owned by this lane
  const int bglob = g * 16 + pb;

  unsigned* ctr = (unsigned*)(ws + OFF_CTR1) + g * 16;
  unsigned short* h0ex = (unsigned short*)(ws + OFF_H0EX) + (size_t)g * 2 * 16 * 256;
  unsigned short* h1ex = (unsigned short*)(ws + OFF_H1EX) + (size_t)g * 2 * 16 * 256;
  float* c0ws = (float*)(ws + OFF_C0);
  float* c1ws = (float*)(ws + OFF_C1);

  __shared__ float ldsT[8 * 256];
  float* t0 = &ldsT[(w * 2 + 0) * 256];
  float* t1 = &ldsT[(w * 2 + 1) * 256];

  // ---- preload weight fragments (stationary for all 673 ticks) ----
  // wave w owns gate-columns n = 16w + fcol; n -> (channel n>>2, gate n&3)
  const int n    = 16 * w + fcol;
  const int grow = (n & 3) * HDIM + m * 16 + (n >> 2);  // row in [4H x H] weight
  short8 wh0[8], wi1[8], wh1[8];
#pragma unroll
  for (int kf = 0; kf < 8; kf++) {
    const int k0 = kf * 32 + kq * 8;
    wh0[kf] = ld_frag8(Whh0, grow, HDIM, k0, mode);
    wi1[kf] = ld_frag8(Wih1, grow, HDIM, k0, mode);
    wh1[kf] = ld_frag8(Whh1, grow, HDIM, k0, mode);
  }
  float wx[4], bb0[4], bb1[4];
#pragma unroll
  for (int gt = 0; gt < 4; gt++) {
    wx[gt]  = ld_scalar(Wih0, gt * HDIM + ch, mode);   // enc_Wih0 is [4H,1]
    bb0[gt] = ld_scalar(b0,   gt * HDIM + ch, mode);
    bb1[gt] = ld_scalar(b1,   gt * HDIM + ch, mode);
  }
  float c0 = 0.f, c1 = 0.f;

  // tick t: layer0 computes step t (t<S), layer1 computes step t-1 (t>=1)
  for (int t = 0; t <= S_LEN; t++) {
    const int pr = (t + 1) & 1, pw = t & 1;
    const unsigned short* a0p = h0ex + pr * (16 * 256) + fcol * 256;
    const unsigned short* a1p = h1ex + pr * (16 * 256) + fcol * 256;
    short8 a0[8], a1[8];
#pragma unroll
    for (int kf = 0; kf < 8; kf++) a0[kf] = *(const short8*)(a0p + kf * 32 + kq * 8);
    if (t >= 1) {
#pragma unroll
      for (int kf = 0; kf < 8; kf++) a1[kf] = *(const short8*)(a1p + kf * 32 + kq * 8);
    }
    f32x4 acc0 = {0.f, 0.f, 0.f, 0.f}, acc1 = {0.f, 0.f, 0.f, 0.f};
    if (t < S_LEN) {
#pragma unroll
      for (int kf = 0; kf < 8; kf++) acc0 = mfma_bf16(a0[kf], wh0[kf], acc0);
    }
    if (t >= 1) {
#pragma unroll
      for (int kf = 0; kf < 8; kf++) {
        acc1 = mfma_bf16(a0[kf], wi1[kf], acc1);   // y0[t-1] = h0[t-1] (same A!)
        acc1 = mfma_bf16(a1[kf], wh1[kf], acc1);
      }
    }
    // transpose C tiles through LDS so each lane owns one (b, ch) with 4 gates contiguous
    if (t < S_LEN) {
#pragma unroll
      for (int i = 0; i < 4; i++) t0[(kq * 4 + i) * 16 + fcol] = acc0[i];
    }
    if (t >= 1) {
#pragma unroll
      for (int i = 0; i < 4; i++) t1[(kq * 4 + i) * 16 + fcol] = acc1[i];
    }
    __syncthreads();
    if (t < S_LEN) {
      const float4 ge = *(const float4*)&t0[pb * 16 + pcl * 4];
      const float x = ld_scalar(feat, (long)bglob * S_LEN + t, mode);
      const float gi = ge.x + x * wx[0] + bb0[0];
      const float gf = ge.y + x * wx[1] + bb0[1];
      const float gg = ge.z + x * wx[2] + bb0[2];
      const float go = ge.w + x * wx[3] + bb0[3];
      c0 = sigm(gf) * c0 + sigm(gi) * tanhf(gg);
      const float h0v = sigm(go) * tanhf(c0);
      h0ex[pw * (16 * 256) + pb * 256 + ch] = f2bf(h0v);
    }
    if (t >= 1) {
      const float4 ge = *(const float4*)&t1[pb * 16 + pcl * 4];
      const float gi = ge.x + bb1[0];
      const float gf = ge.y + bb1[1];
      const float gg = ge.z + bb1[2];
      const float go = ge.w + bb1[3];
      c1 = sigm(gf) * c1 + sigm(gi) * tanhf(gg);
      const float h1v = sigm(go) * tanhf(c1);
      h1ex[pw * (16 * 256) + pb * 256 + ch] = f2bf(h1v);
      if (t == S_LEN) h1ex[1 * (16 * 256) + pb * 256 + ch] = f2bf(h1v);  // dup for decoder init
    }
    group_barrier(ctr, 64u * (unsigned)(t + 1));
  }
  // hand off final cell states (h0 final sits in h0ex parity 1, h1 final duped to parity 1)
  c0ws[(size_t)bglob * HDIM + ch] = c0;
  c1ws[(size_t)bglob * HDIM + ch] = c1;
}

// ============================ decoder ============================
__global__ void __launch_bounds__(256, 1)
dec_kernel(const void* __restrict__ Wih0, const void* __restrict__ Whh0, const void* __restrict__ b0,
           const void* __restrict__ Wih1, const void* __restrict__ Whh1, const void* __restrict__ b1,
           const void* __restrict__ W1, const void* __restrict__ b1h, const void* __restrict__ W2,
           const void* __restrict__ b2, char* __restrict__ ws, void* __restrict__ out) {
  const int mode = (int)*(const unsigned*)(ws + OFF_FLAG);
  const int tid  = threadIdx.x;
  const int lane = tid & 63;
  const int w    = tid >> 6;
  const int bId  = blockIdx.x;
  const int g    = (bId & 7) * 2 + ((bId >> 3) & 1);
  const int m    = bId >> 4;

  const int fcol = lane & 15;
  const int kq   = lane >> 4;
  const int pb   = lane & 15;
  const int pcl  = lane >> 4;
  const int ch   = m * 16 + w * 4 + pcl;
  const int bglob = g * 16 + pb;

  unsigned* ctr = (unsigned*)(ws + OFF_CTR2) + g * 16;
  unsigned short* h0ex = (unsigned short*)(ws + OFF_H0EX) + (size_t)g * 2 * 16 * 256;
  unsigned short* h1ex = (unsigned short*)(ws + OFF_H1EX) + (size_t)g * 2 * 16 * 256;
  float* pred = (float*)(ws + OFF_PRED);
  float* c0ws = (float*)(ws + OFF_C0);
  float* c1ws = (float*)(ws + OFF_C1);

  __shared__ float ldsT[8 * 256];
  __shared__ float part[4 * 256];
  __shared__ float redv[256];
  float* t0 = &ldsT[(w * 2 + 0) * 256];
  float* t1 = &ldsT[(w * 2 + 1) * 256];

  const int n    = 16 * w + fcol;
  const int grow = (n & 3) * HDIM + m * 16 + (n >> 2);
  short8 wh0[8], wi1[8], wh1[8], ww1[2];
#pragma unroll
  for (int kf = 0; kf < 8; kf++) {
    const int k0 = kf * 32 + kq * 8;
    wh0[kf] = ld_frag8(Whh0, grow, HDIM, k0, mode);
    wi1[kf] = ld_frag8(Wih1, grow, HDIM, k0, mode);
    wh1[kf] = ld_frag8(Whh1, grow, HDIM, k0, mode);
  }
#pragma unroll
  for (int kf2 = 0; kf2 < 2; kf2++) {
    const int k0 = w * 64 + kf2 * 32 + kq * 8;   // K-split of head GEMM across waves
    ww1[kf2] = ld_frag8(W1, m * 16 + fcol, HDIM, k0, mode);
  }
  float wx[4], bb0[4], bb1[4];
#pragma unroll
  for (int gt = 0; gt < 4; gt++) {
    wx[gt]  = ld_scalar(Wih0, gt * HDIM + ch, mode);   // dec_Wih0 is [4H,1]
    bb0[gt] = ld_scalar(b0,   gt * HDIM + ch, mode);
    bb1[gt] = ld_scalar(b1,   gt * HDIM + ch, mode);
  }
  const int hb = tid & 15, hcl = tid >> 4;             // head reduce roles
  const float b1hv = ld_scalar(b1h, m * 16 + hcl, mode);
  const float w2v  = ld_scalar(W2,  m * 16 + hcl, mode);
  const float b2v  = ld_scalar(b2, 0, mode);

  float c0 = c0ws[(size_t)bglob * HDIM + ch];
  float c1 = c1ws[(size_t)bglob * HDIM + ch];

  unsigned bar = 0;
  for (int s = 0; s < T_LEN; s++) {
    const int pr = (s + 1) & 1, pw = s & 1;
    // ---------- phase A: layer0 ----------
    float x = 0.f;
    if (s > 0) x = pred[pr * 256 + g * 16 + pb];
    if (s > 0 && m == 0 && tid < 16)
      st_out(out, (size_t)(g * 16 + tid) * T_LEN + (s - 1), pred[pr * 256 + g * 16 + tid], mode);
    {
      const unsigned short* ap = h0ex + pr * (16 * 256) + fcol * 256;
      short8 a0[8];
#pragma unroll
      for (int kf = 0; kf < 8; kf++) a0[kf] = *(const short8*)(ap + kf * 32 + kq * 8);
      f32x4 acc = {0.f, 0.f, 0.f, 0.f};
#pragma unroll
      for (int kf = 0; kf < 8; kf++) acc = mfma_bf16(a0[kf], wh0[kf], acc);
#pragma unroll
      for (int i = 0; i < 4; i++) t0[(kq * 4 + i) * 16 + fcol] = acc[i];
      __syncthreads();
      const float4 ge = *(const float4*)&t0[pb * 16 + pcl * 4];
      const float gi = ge.x + x * wx[0] + bb0[0];
      const float gf = ge.y + x * wx[1] + bb0[1];
      const float gg = ge.z + x * wx[2] + bb0[2];
      const float go = ge.w + x * wx[3] + bb0[3];
      c0 = sigm(gf) * c0 + sigm(gi) * tanhf(gg);
      const float h0v = sigm(go) * tanhf(c0);
      h0ex[pw * (16 * 256) + pb * 256 + ch] = f2bf(h0v);
    }
    group_barrier(ctr, 64u * (++bar));
    // ---------- phase B: layer1 ----------
    {
      const unsigned short* ayp = h0ex + pw * (16 * 256) + fcol * 256;
      const unsigned short* a1p = h1ex + pr * (16 * 256) + fcol * 256;
      short8 ay[8], a1[8];
#pragma unroll
      for (int kf = 0; kf < 8; kf++) {
        ay[kf] = *(const short8*)(ayp + kf * 32 + kq * 8);
        a1[kf] = *(const short8*)(a1p + kf * 32 + kq * 8);
      }
      f32x4 acc = {0.f, 0.f, 0.f, 0.f};
#pragma unroll
      for (int kf = 0; kf < 8; kf++) {
        acc = mfma_bf16(ay[kf], wi1[kf], acc);
        acc = mfma_bf16(a1[kf], wh1[kf], acc);
      }
#pragma unroll
      for (int i = 0; i < 4; i++) t1[(kq * 4 + i) * 16 + fcol] = acc[i];
      __syncthreads();
      const float4 ge = *(const float4*)&t1[pb * 16 + pcl * 4];
      const float gi = ge.x + bb1[0];
      const float gf = ge.y + bb1[1];
      const float gg = ge.z + bb1[2];
      const float go = ge.w + bb1[3];
      c1 = sigm(gf) * c1 + sigm(gi) * tanhf(gg);
      const float h1v = sigm(go) * tanhf(c1);
      h1ex[pw * (16 * 256) + pb * 256 + ch] = f2bf(h1v);
      if (m == 0 && tid < 16) pred[pw * 256 + g * 16 + tid] = 0.f;   // prep accumulator
    }
    group_barrier(ctr, 64u * (++bar));
    // ---------- phase C: head (Linear->ReLU->Linear), K-split across waves ----------
    {
      const unsigned short* ahp = h1ex + pw * (16 * 256) + fcol * 256 + w * 64;
      const short8 ah0 = *(const short8*)(ahp + kq * 8);
      const short8 ah1 = *(const short8*)(ahp + 32 + kq * 8);
      f32x4 acc = {0.f, 0.f, 0.f, 0.f};
      acc = mfma_bf16(ah0, ww1[0], acc);
      acc = mfma_bf16(ah1, ww1[1], acc);
#pragma unroll
      for (int i = 0; i < 4; i++) part[w * 256 + (kq * 4 + i) * 16 + fcol] = acc[i];
      __syncthreads();
      float hid = part[0 * 256 + hb * 16 + hcl] + part[1 * 256 + hb * 16 + hcl]
                + part[2 * 256 + hb * 16 + hcl] + part[3 * 256 + hb * 16 + hcl] + b1hv;
      hid = fmaxf(hid, 0.f);
      redv[hcl * 16 + hb] = hid * w2v;
      __syncthreads();
      if (tid < 16) {
        float a = (m == 0) ? b2v : 0.f;
#pragma unroll
        for (int cc = 0; cc < 16; cc++) a += redv[cc * 16 + tid];
        __hip_atomic_fetch_add(&pred[pw * 256 + g * 16 + tid], a,
                               __ATOMIC_RELAXED, __HIP_MEMORY_SCOPE_AGENT);
      }
      __syncthreads();
    }
    group_barrier(ctr, 64u * (++bar));
  }
  if (m == 0 && tid < 16)
    st_out(out, (size_t)(g * 16 + tid) * T_LEN + (T_LEN - 1),
           pred[((T_LEN - 1) & 1) * 256 + g * 16 + tid], mode);
}

extern "C" void kernel_launch(void* const* d_in, const int* in_sizes, int n_in,
                              void* d_out, int out_size, void* d_ws, size_t ws_size,
                              hipStream_t stream) {
  char* ws = (char*)d_ws;
  // re-zero barrier counters + exchange buffers + pred every launch (replay-safe)
  hipMemsetAsync(ws, 0, ZERO_END, stream);
  detect_mode<<<1, 64, 0, stream>>>((const unsigned*)d_in[0], (unsigned*)(ws + OFF_FLAG));
  enc_kernel<<<256, 256, 0, stream>>>(d_in[0], d_in[1], d_in[2], d_in[3],
                                      d_in[4], d_in[5], d_in[6], ws);
  dec_kernel<<<256, 256, 0, stream>>>(d_in[7], d_in[8], d_in[9], d_in[10], d_in[11], d_in[12],
                                      d_in[13], d_in[14], d_in[15], d_in[16], ws, d_out);
}

// Round 3
// 11120.985 us; speedup vs baseline: 2.3878x; 2.3878x over previous
//
#include <hip/hip_runtime.h>

// Seq2Seq LSTM forecaster: H=256, B=256, S=672, T=96.
// Round 3: fence-free tagged-dataflow exchange, handoff races fixed.
//   - 256 wgs = 16 batch-groups x 16 channel-shards, weights register-stationary.
//   - Exchange words carry their own tag: u32 = tag<<16 | bf16, RELAXED AGENT atomics
//     (IC-coherent, no L2 writeback/invalidate storms). No fences, no barriers.
//   - Steady-state slabs are two-generation safe via the produce/consume chain.
//   - Encoder->decoder handoff uses dedicated write-once fin buffers (tag 1), written
//     AFTER the encoder wg's final slab polls -> no one-generation overwrite races.
//   - All spins bounded (fail-fast instead of deadlock).

#define S_LEN 672
#define T_LEN 96
#define HDIM  256
#define G4U   4096          // u32 words per parity slab per group (16 b x 256 ch)
#define SPIN_MAX (1 << 23)

typedef short short8 __attribute__((ext_vector_type(8)));
typedef float f32x4  __attribute__((ext_vector_type(4)));
typedef unsigned long long u64;

// ---- workspace layout (bytes) ----
#define OFF_FLAG 0
#define OFF_H0EX 4096                              // u32 [16g][2 parity][16b][256ch]
#define OFF_H1EX (OFF_H0EX + 16*2*G4U*4)
#define OFF_PART (OFF_H1EX + 16*2*G4U*4)           // u64 [2 parity][16g][16m][16b]
#define OFF_FIN0 (OFF_PART + 2*16*256*8)           // u32 [16g][16b][256ch] h0 final
#define OFF_FIN1 (OFF_FIN0 + 16*G4U*4)             // u32 [16g][16b][256ch] h1 final
#define ZERO_END (OFF_FIN1 + 16*G4U*4)
#define OFF_C0   ZERO_END                          // f32 [256][256]
#define OFF_C1   (OFF_C0 + 256*256*4)

__device__ __forceinline__ unsigned short f2bf(float f) {
  unsigned u = __float_as_uint(f);
  u += 0x7FFFu + ((u >> 16) & 1u);
  return (unsigned short)(u >> 16);
}
__device__ __forceinline__ float bf2f(unsigned short s) {
  return __uint_as_float(((unsigned)s) << 16);
}
__device__ __forceinline__ float ld_scalar(const void* p, long idx, int mode) {
  if (mode) return bf2f(((const unsigned short*)p)[idx]);
  return ((const float*)p)[idx];
}
__device__ __forceinline__ short8 ld_frag8(const void* p, long row, long ld, long k0, int mode) {
  if (mode) {
    return *(const short8*)((const unsigned short*)p + row * ld + k0);
  } else {
    const float* f = (const float*)p + row * ld + k0;
    short8 r;
#pragma unroll
    for (int i = 0; i < 8; i++) r[i] = (short)f2bf(f[i]);
    return r;
  }
}
__device__ __forceinline__ void st_out(void* out, size_t idx, float v, int mode) {
  if (mode) ((unsigned short*)out)[idx] = f2bf(v);
  else      ((float*)out)[idx] = v;
}
__device__ __forceinline__ float sigm(float x) { return 1.f / (1.f + __expf(-x)); }

__device__ __forceinline__ f32x4 mfma_bf16(short8 a, short8 b, f32x4 c) {
  return __builtin_amdgcn_mfma_f32_16x16x32_bf16(a, b, c, 0, 0, 0);
}

// relaxed agent-scope atomics (IC-coherent), NO fences
__device__ __forceinline__ u64 ald64(const u64* p) {
  return __hip_atomic_load(p, __ATOMIC_RELAXED, __HIP_MEMORY_SCOPE_AGENT);
}
__device__ __forceinline__ void ast32(unsigned* p, unsigned v) {
  __hip_atomic_store(p, v, __ATOMIC_RELAXED, __HIP_MEMORY_SCOPE_AGENT);
}
__device__ __forceinline__ void ast64(u64* p, u64 v) {
  __hip_atomic_store(p, v, __ATOMIC_RELAXED, __HIP_MEMORY_SCOPE_AGENT);
}

// Poll-read a full K=256 A-operand row (8 frags). Tagged words: (tg<<16)|bf16.
__device__ __forceinline__ void poll8(const unsigned* __restrict__ rowbase, int kq,
                                      unsigned tg, short8* __restrict__ out) {
#pragma unroll
  for (int half = 0; half < 2; half++) {
    u64 v[16];
    unsigned bad;
    int spin = 0;
    do {
      bad = 0u;
#pragma unroll
      for (int q = 0; q < 4; q++) {
        const u64* pp = (const u64*)(rowbase + (half * 4 + q) * 32 + kq * 8);
#pragma unroll
        for (int j = 0; j < 4; j++) {
          const u64 x = ald64(pp + j);
          v[q * 4 + j] = x;
          bad |= (((unsigned)(x >> 16)) & 0xFFFFu) ^ tg;
          bad |= ((unsigned)(x >> 48)) ^ tg;
        }
      }
      if (bad) { __builtin_amdgcn_s_sleep(1); if (++spin > SPIN_MAX) break; }
    } while (bad != 0u);
#pragma unroll
    for (int q = 0; q < 4; q++) {
      short8 f;
#pragma unroll
      for (int j = 0; j < 4; j++) {
        const u64 x = v[q * 4 + j];
        f[2 * j]     = (short)(x & 0xFFFFu);
        f[2 * j + 1] = (short)((x >> 32) & 0xFFFFu);
      }
      out[half * 4 + q] = f;
    }
  }
}

// Poll-read 2 frags (64 channels) at `p` for the head GEMM.
__device__ __forceinline__ void poll2(const unsigned* __restrict__ p, unsigned tg,
                                      short8* __restrict__ f0, short8* __restrict__ f1) {
  u64 v[8];
  unsigned bad;
  int spin = 0;
  do {
    bad = 0u;
#pragma unroll
    for (int k2 = 0; k2 < 2; k2++) {
      const u64* pp = (const u64*)(p + k2 * 32);
#pragma unroll
      for (int j = 0; j < 4; j++) {
        const u64 x = ald64(pp + j);
        v[k2 * 4 + j] = x;
        bad |= (((unsigned)(x >> 16)) & 0xFFFFu) ^ tg;
        bad |= ((unsigned)(x >> 48)) ^ tg;
      }
    }
    if (bad) { __builtin_amdgcn_s_sleep(1); if (++spin > SPIN_MAX) break; }
  } while (bad != 0u);
  short8 a, b;
#pragma unroll
  for (int j = 0; j < 4; j++) {
    u64 x = v[j];
    a[2 * j] = (short)(x & 0xFFFFu); a[2 * j + 1] = (short)((x >> 32) & 0xFFFFu);
    x = v[4 + j];
    b[2 * j] = (short)(x & 0xFFFFu); b[2 * j + 1] = (short)((x >> 32) & 0xFFFFu);
  }
  *f0 = a; *f1 = b;
}

// ---- dtype detector ----
__global__ void detect_mode(const unsigned* __restrict__ feat, unsigned* __restrict__ flag) {
  const int t = threadIdx.x;
  int cnt = 0;
#pragma unroll
  for (int i = 0; i < 8; i++) {
    const unsigned wv = feat[t * 8 + i];
    const unsigned e = (wv >> 7) & 0xFFu;
    cnt += (e >= 100u && e <= 130u) ? 1 : 0;
  }
#pragma unroll
  for (int o = 32; o > 0; o >>= 1) cnt += __shfl_down(cnt, o, 64);
  if (t == 0) flag[0] = (cnt >= 256) ? 1u : 0u;
}

// ============================ encoder ============================
// Tick t (0..672): layer0 computes step t (t<672), layer1 computes step t-1 (t>=1).
// h0(t): parity t&1, tag t+1. h1(tau) (at tick tau+1): parity (tau+1)&1, tag tau+2.
// Reads at tick t: a0 = h0(t-1) tag t; a1 = h1(t-2) tag t; both parity (t+1)&1.
// At t=672, AFTER final polls: publish h0(671)/h1(671) to fin buffers (tag 1).
__global__ void __launch_bounds__(256, 1)
enc_kernel(const void* __restrict__ feat,
           const void* __restrict__ Wih0, const void* __restrict__ Whh0, const void* __restrict__ b0,
           const void* __restrict__ Wih1, const void* __restrict__ Whh1, const void* __restrict__ b1,
           char* __restrict__ ws) {
  const int mode = (int)*(const unsigned*)(ws + OFF_FLAG);
  const int tid  = threadIdx.x;
  const int lane = tid & 63;
  const int w    = tid >> 6;
  const int bId  = blockIdx.x;
  const int g    = (bId & 7) * 2 + ((bId >> 3) & 1);
  const int m    = bId >> 4;

  const int fcol = lane & 15;
  const int kq   = lane >> 4;
  const int pb   = lane & 15;
  const int pcl  = lane >> 4;
  const int ch   = m * 16 + w * 4 + pcl;
  const int bglob = g * 16 + pb;

  unsigned* h0g = (unsigned*)(ws + OFF_H0EX) + (size_t)g * 2 * G4U;
  unsigned* h1g = (unsigned*)(ws + OFF_H1EX) + (size_t)g * 2 * G4U;
  unsigned* h0f = (unsigned*)(ws + OFF_FIN0) + (size_t)g * G4U;
  unsigned* h1f = (unsigned*)(ws + OFF_FIN1) + (size_t)g * G4U;
  float* c0ws = (float*)(ws + OFF_C0);
  float* c1ws = (float*)(ws + OFF_C1);

  __shared__ float ldsT[8 * 256];
  float* t0 = &ldsT[(w * 2 + 0) * 256];
  float* t1 = &ldsT[(w * 2 + 1) * 256];

  const int n    = 16 * w + fcol;
  const int grow = (n & 3) * HDIM + m * 16 + (n >> 2);
  short8 wh0[8], wi1[8], wh1[8];
#pragma unroll
  for (int kf = 0; kf < 8; kf++) {
    const int k0 = kf * 32 + kq * 8;
    wh0[kf] = ld_frag8(Whh0, grow, HDIM, k0, mode);
    wi1[kf] = ld_frag8(Wih1, grow, HDIM, k0, mode);
    wh1[kf] = ld_frag8(Whh1, grow, HDIM, k0, mode);
  }
  float wx[4], bb0[4], bb1[4];
#pragma unroll
  for (int gt = 0; gt < 4; gt++) {
    wx[gt]  = ld_scalar(Wih0, gt * HDIM + ch, mode);
    bb0[gt] = ld_scalar(b0,   gt * HDIM + ch, mode);
    bb1[gt] = ld_scalar(b1,   gt * HDIM + ch, mode);
  }
  float c0 = 0.f, c1 = 0.f, h0keep = 0.f;

  for (int t = 0; t <= S_LEN; t++) {
    const int pr = (t + 1) & 1, pw = t & 1;
    const unsigned tg = (unsigned)t;
    short8 a0[8], a1[8];
    if (t >= 1) poll8(h0g + pr * G4U + fcol * 256, kq, tg, a0);
    if (t >= 2) poll8(h1g + pr * G4U + fcol * 256, kq, tg, a1);

    f32x4 acc0 = {0.f, 0.f, 0.f, 0.f}, acc1 = {0.f, 0.f, 0.f, 0.f};
    if (t >= 1 && t < S_LEN) {
#pragma unroll
      for (int kf = 0; kf < 8; kf++) acc0 = mfma_bf16(a0[kf], wh0[kf], acc0);
    }
    if (t >= 1) {
#pragma unroll
      for (int kf = 0; kf < 8; kf++) acc1 = mfma_bf16(a0[kf], wi1[kf], acc1);
      if (t >= 2) {
#pragma unroll
        for (int kf = 0; kf < 8; kf++) acc1 = mfma_bf16(a1[kf], wh1[kf], acc1);
      }
    }
    // wave-local LDS transpose (each wave owns its slice)
    if (t < S_LEN) {
#pragma unroll
      for (int i = 0; i < 4; i++) t0[(kq * 4 + i) * 16 + fcol] = acc0[i];
    }
    if (t >= 1) {
#pragma unroll
      for (int i = 0; i < 4; i++) t1[(kq * 4 + i) * 16 + fcol] = acc1[i];
    }
    if (t < S_LEN) {
      const float4 ge = *(const float4*)&t0[pb * 16 + pcl * 4];
      const float x = ld_scalar(feat, (long)bglob * S_LEN + t, mode);
      const float gi = ge.x + x * wx[0] + bb0[0];
      const float gf = ge.y + x * wx[1] + bb0[1];
      const float gg = ge.z + x * wx[2] + bb0[2];
      const float go = ge.w + x * wx[3] + bb0[3];
      c0 = sigm(gf) * c0 + sigm(gi) * tanhf(gg);
      const float h0v = sigm(go) * tanhf(c0);
      h0keep = h0v;
      ast32(h0g + pw * G4U + pb * 256 + ch, ((unsigned)(t + 1) << 16) | f2bf(h0v));
    }
    if (t >= 1) {
      const float4 ge = *(const float4*)&t1[pb * 16 + pcl * 4];
      const float gi = ge.x + bb1[0];
      const float gf = ge.y + bb1[1];
      const float gg = ge.z + bb1[2];
      const float go = ge.w + bb1[3];
      c1 = sigm(gf) * c1 + sigm(gi) * tanhf(gg);
      const float h1v = sigm(go) * tanhf(c1);
      ast32(h1g + pw * G4U + pb * 256 + ch, ((unsigned)(t + 1) << 16) | f2bf(h1v));
      if (t == S_LEN) {
        // AFTER this wg's final slab polls: publish finals (write-once, tag 1)
        ast32(h0f + pb * 256 + ch, (1u << 16) | f2bf(h0keep));
        ast32(h1f + pb * 256 + ch, (1u << 16) | f2bf(h1v));
      }
    }
  }
  c0ws[(size_t)bglob * HDIM + ch] = c0;
  c1ws[(size_t)bglob * HDIM + ch] = c1;
}

// ============================ decoder ============================
// Tags: dec h0(s): parity s&1, tag 673+s. dec h1(s): parity s&1, tag 674+s.
// pred partial(s): parity s&1, tag s+1 (u64). s=0 reads come from fin buffers (tag 1).
__global__ void __launch_bounds__(256, 1)
dec_kernel(const void* __restrict__ Wih0, const void* __restrict__ Whh0, const void* __restrict__ b0,
           const void* __restrict__ Wih1, const void* __restrict__ Whh1, const void* __restrict__ b1,
           const void* __restrict__ W1, const void* __restrict__ b1h, const void* __restrict__ W2,
           const void* __restrict__ b2, char* __restrict__ ws, void* __restrict__ out) {
  const int mode = (int)*(const unsigned*)(ws + OFF_FLAG);
  const int tid  = threadIdx.x;
  const int lane = tid & 63;
  const int w    = tid >> 6;
  const int bId  = blockIdx.x;
  const int g    = (bId & 7) * 2 + ((bId >> 3) & 1);
  const int m    = bId >> 4;

  const int fcol = lane & 15;
  const int kq   = lane >> 4;
  const int pb   = lane & 15;
  const int pcl  = lane >> 4;
  const int ch   = m * 16 + w * 4 + pcl;
  const int bglob = g * 16 + pb;

  unsigned* h0g = (unsigned*)(ws + OFF_H0EX) + (size_t)g * 2 * G4U;
  unsigned* h1g = (unsigned*)(ws + OFF_H1EX) + (size_t)g * 2 * G4U;
  unsigned* h0f = (unsigned*)(ws + OFF_FIN0) + (size_t)g * G4U;
  unsigned* h1f = (unsigned*)(ws + OFF_FIN1) + (size_t)g * G4U;
  u64* partial  = (u64*)(ws + OFF_PART);
  float* c0ws = (float*)(ws + OFF_C0);
  float* c1ws = (float*)(ws + OFF_C1);

  __shared__ float ldsT[8 * 256];
  __shared__ float part[4 * 256];
  __shared__ float redv[256];
  __shared__ float xacc[256];
  float* t0 = &ldsT[(w * 2 + 0) * 256];
  float* t1 = &ldsT[(w * 2 + 1) * 256];

  const int n    = 16 * w + fcol;
  const int grow = (n & 3) * HDIM + m * 16 + (n >> 2);
  short8 wh0[8], wi1[8], wh1[8], ww1[2];
#pragma unroll
  for (int kf = 0; kf < 8; kf++) {
    const int k0 = kf * 32 + kq * 8;
    wh0[kf] = ld_frag8(Whh0, grow, HDIM, k0, mode);
    wi1[kf] = ld_frag8(Wih1, grow, HDIM, k0, mode);
    wh1[kf] = ld_frag8(Whh1, grow, HDIM, k0, mode);
  }
#pragma unroll
  for (int kf2 = 0; kf2 < 2; kf2++) {
    const int k0 = w * 64 + kf2 * 32 + kq * 8;
    ww1[kf2] = ld_frag8(W1, m * 16 + fcol, HDIM, k0, mode);
  }
  float wx[4], bb0[4], bb1[4];
#pragma unroll
  for (int gt = 0; gt < 4; gt++) {
    wx[gt]  = ld_scalar(Wih0, gt * HDIM + ch, mode);
    bb0[gt] = ld_scalar(b0,   gt * HDIM + ch, mode);
    bb1[gt] = ld_scalar(b1,   gt * HDIM + ch, mode);
  }
  const int hb = tid & 15, hcl = tid >> 4;
  const float b1hv = ld_scalar(b1h, m * 16 + hcl, mode);
  const float w2v  = ld_scalar(W2,  m * 16 + hcl, mode);
  const float b2v  = ld_scalar(b2, 0, mode);

  float c0 = c0ws[(size_t)bglob * HDIM + ch];
  float c1 = c1ws[(size_t)bglob * HDIM + ch];

  const int pm = tid >> 4, pbb = tid & 15;   // partial-read roles

  for (int s = 0; s < T_LEN; s++) {
    const int ppr = (s - 1) & 1;
    const int pcur = s & 1;
    // ---------- phase A: gather pred(s-1), layer0 ----------
    float x = 0.f;
    if (s > 0) {
      const u64* pp = partial + ((size_t)ppr * 16 + g) * 256 + pm * 16 + pbb;
      u64 pv = ald64(pp);
      int spin = 0;
      while ((unsigned)(pv >> 32) != (unsigned)s) {
        __builtin_amdgcn_s_sleep(1);
        if (++spin > SPIN_MAX) break;
        pv = ald64(pp);
      }
      xacc[pbb * 16 + pm] = __uint_as_float((unsigned)(pv & 0xFFFFFFFFu));
      __syncthreads();
      x = 0.f;
#pragma unroll
      for (int j = 0; j < 16; j++) x += xacc[pb * 16 + j];
      if (m == 0 && tid < 16)
        st_out(out, (size_t)(g * 16 + tid) * T_LEN + (s - 1), x, mode);
    }
    {
      short8 a0[8];
      const unsigned* a0base = (s == 0) ? (h0f + fcol * 256)
                                        : (h0g + ppr * G4U + fcol * 256);
      poll8(a0base, kq, (s == 0) ? 1u : (unsigned)(672 + s), a0);
      f32x4 acc = {0.f, 0.f, 0.f, 0.f};
#pragma unroll
      for (int kf = 0; kf < 8; kf++) acc = mfma_bf16(a0[kf], wh0[kf], acc);
#pragma unroll
      for (int i = 0; i < 4; i++) t0[(kq * 4 + i) * 16 + fcol] = acc[i];
      const float4 ge = *(const float4*)&t0[pb * 16 + pcl * 4];
      const float gi = ge.x + x * wx[0] + bb0[0];
      const float gf = ge.y + x * wx[1] + bb0[1];
      const float gg = ge.z + x * wx[2] + bb0[2];
      const float go = ge.w + x * wx[3] + bb0[3];
      c0 = sigm(gf) * c0 + sigm(gi) * tanhf(gg);
      const float h0v = sigm(go) * tanhf(c0);
      ast32(h0g + pcur * G4U + pb * 256 + ch, ((unsigned)(673 + s) << 16) | f2bf(h0v));
    }
    // ---------- phase B: layer1 ----------
    {
      short8 ay[8], a1[8];
      poll8(h0g + pcur * G4U + fcol * 256, kq, (unsigned)(673 + s), ay);
      const unsigned* a1base = (s == 0) ? (h1f + fcol * 256)
                                        : (h1g + ppr * G4U + fcol * 256);
      poll8(a1base, kq, (s == 0) ? 1u : (unsigned)(673 + s), a1);
      f32x4 acc = {0.f, 0.f, 0.f, 0.f};
#pragma unroll
      for (int kf = 0; kf < 8; kf++) {
        acc = mfma_bf16(ay[kf], wi1[kf], acc);
        acc = mfma_bf16(a1[kf], wh1[kf], acc);
      }
#pragma unroll
      for (int i = 0; i < 4; i++) t1[(kq * 4 + i) * 16 + fcol] = acc[i];
      const float4 ge = *(const float4*)&t1[pb * 16 + pcl * 4];
      const float gi = ge.x + bb1[0];
      const float gf = ge.y + bb1[1];
      const float gg = ge.z + bb1[2];
      const float go = ge.w + bb1[3];
      c1 = sigm(gf) * c1 + sigm(gi) * tanhf(gg);
      const float h1v = sigm(go) * tanhf(c1);
      ast32(h1g + pcur * G4U + pb * 256 + ch, ((unsigned)(674 + s) << 16) | f2bf(h1v));
    }
    // ---------- phase C: head (Linear->ReLU->Linear), publish tagged partial ----------
    {
      short8 ah0, ah1;
      poll2(h1g + pcur * G4U + fcol * 256 + w * 64 + kq * 8, (unsigned)(674 + s), &ah0, &ah1);
      f32x4 acc = {0.f, 0.f, 0.f, 0.f};
      acc = mfma_bf16(ah0, ww1[0], acc);
      acc = mfma_bf16(ah1, ww1[1], acc);
#pragma unroll
      for (int i = 0; i < 4; i++) part[w * 256 + (kq * 4 + i) * 16 + fcol] = acc[i];
      __syncthreads();
      float hid = part[0 * 256 + hb * 16 + hcl] + part[1 * 256 + hb * 16 + hcl]
                + part[2 * 256 + hb * 16 + hcl] + part[3 * 256 + hb * 16 + hcl] + b1hv;
      hid = fmaxf(hid, 0.f);
      redv[hcl * 16 + hb] = hid * w2v;
      __syncthreads();
      if (tid < 16) {
        float a = (m == 0) ? b2v : 0.f;
#pragma unroll
        for (int cc = 0; cc < 16; cc++) a += redv[cc * 16 + tid];
        ast64(partial + ((size_t)pcur * 16 + g) * 256 + m * 16 + tid,
              ((u64)(unsigned)(s + 1) << 32) | (u64)__float_as_uint(a));
      }
      __syncthreads();
    }
  }
  // final output column: pred(T-1), partials tag T_LEN at parity (T-1)&1 = 1
  if (m == 0) {
    const u64* pp = partial + ((size_t)1 * 16 + g) * 256 + pm * 16 + pbb;
    u64 pv = ald64(pp);
    int spin = 0;
    while ((unsigned)(pv >> 32) != (unsigned)T_LEN) {
      __builtin_amdgcn_s_sleep(1);
      if (++spin > SPIN_MAX) break;
      pv = ald64(pp);
    }
    xacc[pbb * 16 + pm] = __uint_as_float((unsigned)(pv & 0xFFFFFFFFu));
    __syncthreads();
    if (tid < 16) {
      float x = 0.f;
#pragma unroll
      for (int j = 0; j < 16; j++) x += xacc[tid * 16 + j];
      st_out(out, (size_t)(g * 16 + tid) * T_LEN + (T_LEN - 1), x, mode);
    }
  }
}

extern "C" void kernel_launch(void* const* d_in, const int* in_sizes, int n_in,
                              void* d_out, int out_size, void* d_ws, size_t ws_size,
                              hipStream_t stream) {
  char* ws = (char*)d_ws;
  // zero all tags/partials/fin every launch (replay-safe: tag 0 == empty)
  hipMemsetAsync(ws, 0, ZERO_END, stream);
  detect_mode<<<1, 64, 0, stream>>>((const unsigned*)d_in[0], (unsigned*)(ws + OFF_FLAG));
  enc_kernel<<<256, 256, 0, stream>>>(d_in[0], d_in[1], d_in[2], d_in[3],
                                      d_in[4], d_in[5], d_in[6], ws);
  dec_kernel<<<256, 256, 0, stream>>>(d_in[7], d_in[8], d_in[9], d_in[10], d_in[11], d_in[12],
                                      d_in[13], d_in[14], d_in[15], d_in[16], ws, d_out);
}

// Round 6
// 8491.310 us; speedup vs baseline: 3.1272x; 1.3097x over previous
//
#include <hip/hip_runtime.h>

// Seq2Seq LSTM forecaster: H=256, B=256, S=672, T=96.
// Round 6 = round 5 resubmitted (container died before r5 ever ran) + fail-fast spins.
//   - 256 wgs = 16 batch-groups x 16 channel-shards, weights register-stationary.
//   - Data plane: asm global_load/store with `sc0 sc1` (coherence-point access),
//     batched 8x dwordx4 per operand with ONE s_waitcnt vmcnt(0).
//   - Control plane: per-wave epoch flags via compiler relaxed AGENT atomics
//     (round-3-proven cross-XCD coherent), 64-lane batched poll + __all.
//   - Producer: data stores -> s_waitcnt vmcnt(0) (drain to coherence point) -> flag.
//   - Swapped MFMA (weights=A, h=B): acc[i] = gate i of (channel, batch) in-lane;
//     encoder has zero LDS and zero __syncthreads.
//   - SPIN_MAX 2^14: worst-case total spin ~seconds, never a wedged container.

#define S_LEN 672
#define T_LEN 96
#define HDIM  256
#define SPIN_MAX (1 << 14)

typedef short short8 __attribute__((ext_vector_type(8)));
typedef float f32x4  __attribute__((ext_vector_type(4)));
typedef unsigned short u16;

// ---- workspace layout (bytes) ----
#define OFF_FLAG 0                                  // dtype mode flag
#define OFF_FE   1024                               // enc flags u32 [16g][16m*4w]
#define OFF_FD   (OFF_FE + 16*64*4)                 // dec flags u32 [16g][16m*4w]
#define OFF_PART (OFF_FD + 16*64*4)                 // f32 [2][16g][16m][16b]
#define ZERO_END (OFF_PART + 2*16*256*4)
#define OFF_H0   ZERO_END                           // u16 [16g][2][16b][256ch]
#define OFF_H1   (OFF_H0 + 16*2*4096*2)
#define OFF_F0   (OFF_H1 + 16*2*4096*2)             // u16 [16g][16b][256ch] h0 final
#define OFF_F1   (OFF_F0 + 16*4096*2)               // u16 [16g][16b][256ch] h1 final
#define OFF_C0   (OFF_F1 + 16*4096*2)               // f32 [256][256]
#define OFF_C1   (OFF_C0 + 256*256*4)

__device__ __forceinline__ unsigned short f2bf(float f) {
  unsigned u = __float_as_uint(f);
  u += 0x7FFFu + ((u >> 16) & 1u);
  return (unsigned short)(u >> 16);
}
__device__ __forceinline__ float bf2f(unsigned short s) {
  return __uint_as_float(((unsigned)s) << 16);
}
__device__ __forceinline__ float ld_scalar(const void* p, long idx, int mode) {
  if (mode) return bf2f(((const u16*)p)[idx]);
  return ((const float*)p)[idx];
}
__device__ __forceinline__ short8 ld_frag8(const void* p, long row, long ld, long k0, int mode) {
  if (mode) {
    return *(const short8*)((const u16*)p + row * ld + k0);
  } else {
    const float* f = (const float*)p + row * ld + k0;
    short8 r;
#pragma unroll
    for (int i = 0; i < 8; i++) r[i] = (short)f2bf(f[i]);
    return r;
  }
}
__device__ __forceinline__ void st_out(void* out, size_t idx, float v, int mode) {
  if (mode) ((u16*)out)[idx] = f2bf(v);
  else      ((float*)out)[idx] = v;
}
__device__ __forceinline__ float sigm(float x) { return 1.f / (1.f + __expf(-x)); }

__device__ __forceinline__ f32x4 mfma_bf16(short8 a, short8 b, f32x4 c) {
  return __builtin_amdgcn_mfma_f32_16x16x32_bf16(a, b, c, 0, 0, 0);
}

// ---- agent-coherent data plane (sc0 sc1 = coherence-point access) ----
__device__ __forceinline__ void issue8(const u16* base, short8* t) {
  asm volatile(
    "global_load_dwordx4 %0, %8, off sc0 sc1\n\t"
    "global_load_dwordx4 %1, %8, off offset:64 sc0 sc1\n\t"
    "global_load_dwordx4 %2, %8, off offset:128 sc0 sc1\n\t"
    "global_load_dwordx4 %3, %8, off offset:192 sc0 sc1\n\t"
    "global_load_dwordx4 %4, %8, off offset:256 sc0 sc1\n\t"
    "global_load_dwordx4 %5, %8, off offset:320 sc0 sc1\n\t"
    "global_load_dwordx4 %6, %8, off offset:384 sc0 sc1\n\t"
    "global_load_dwordx4 %7, %8, off offset:448 sc0 sc1"
    : "=&v"(t[0]), "=&v"(t[1]), "=&v"(t[2]), "=&v"(t[3]),
      "=&v"(t[4]), "=&v"(t[5]), "=&v"(t[6]), "=&v"(t[7])
    : "v"(base) : "memory");
}
__device__ __forceinline__ void issue2(const u16* base, short8* t) {
  asm volatile(
    "global_load_dwordx4 %0, %2, off sc0 sc1\n\t"
    "global_load_dwordx4 %1, %2, off offset:64 sc0 sc1"
    : "=&v"(t[0]), "=&v"(t[1]) : "v"(base) : "memory");
}
__device__ __forceinline__ void st16(u16* p, unsigned short v) {
  asm volatile("global_store_short %0, %1, off sc0 sc1"
               :: "v"(p), "v"((unsigned)v) : "memory");
}
__device__ __forceinline__ void stf32(float* p, float v) {
  asm volatile("global_store_dword %0, %1, off sc0 sc1"
               :: "v"(p), "v"(v) : "memory");
}
__device__ __forceinline__ float ldf32(const float* p) {
  float v;
  asm volatile("global_load_dword %0, %1, off sc0 sc1\n\ts_waitcnt vmcnt(0)"
               : "=&v"(v) : "v"(p) : "memory");
  __builtin_amdgcn_sched_barrier(0);
  return v;
}
__device__ __forceinline__ void waitv0() {
  asm volatile("s_waitcnt vmcnt(0)" ::: "memory");
  __builtin_amdgcn_sched_barrier(0);
}

// ---- control plane: relaxed AGENT atomics (round-3-proven cross-XCD coherent) ----
// Drain this wave's data stores to the coherence point, then lane0 publishes epoch.
__device__ __forceinline__ void publish(unsigned* fa, unsigned e) {
  asm volatile("s_waitcnt vmcnt(0)" ::: "memory");
  if ((threadIdx.x & 63) == 0)
    __hip_atomic_store(fa, e, __ATOMIC_RELAXED, __HIP_MEMORY_SCOPE_AGENT);
}
// 64 lanes poll 64 per-(member,wave) flags; wave proceeds when ALL >= E.
__device__ __forceinline__ void pollge(const unsigned* flags, unsigned E) {
  const unsigned* addr = flags + (threadIdx.x & 63);
  int spin = 0;
  while (!__all(__hip_atomic_load(addr, __ATOMIC_RELAXED, __HIP_MEMORY_SCOPE_AGENT) >= E)) {
    __builtin_amdgcn_s_sleep(1);
    if (++spin > SPIN_MAX) break;
  }
}

// ---- dtype detector ----
__global__ void detect_mode(const unsigned* __restrict__ feat, unsigned* __restrict__ flag) {
  const int t = threadIdx.x;
  int cnt = 0;
#pragma unroll
  for (int i = 0; i < 8; i++) {
    const unsigned wv = feat[t * 8 + i];
    const unsigned e = (wv >> 7) & 0xFFu;
    cnt += (e >= 100u && e <= 130u) ? 1 : 0;
  }
#pragma unroll
  for (int o = 32; o > 0; o >>= 1) cnt += __shfl_down(cnt, o, 64);
  if (t == 0) flag[0] = (cnt >= 256) ? 1u : 0u;
}

// ============================ encoder ============================
// Tick t (0..672): layer0 computes step t (t<672), layer1 computes step t-1 (t>=1).
// Per-wave flag after tick t = t+1 (covers h0(t)/h1(t-1) stores, drained). Tick-t
// reads poll >= t. Slab parity: h(t) at t&1; tick-t reads at (t+1)&1. Two-generation
// overwrite safety: writer at t+2 polled >= t+2 => all tick-(t+1) readers done.
__global__ void __launch_bounds__(256, 1)
enc_kernel(const void* __restrict__ feat,
           const void* __restrict__ Wih0, const void* __restrict__ Whh0, const void* __restrict__ b0,
           const void* __restrict__ Wih1, const void* __restrict__ Whh1, const void* __restrict__ b1,
           char* __restrict__ ws) {
  const int mode = (int)*(const unsigned*)(ws + OFF_FLAG);
  const int lane = threadIdx.x & 63;
  const int w    = threadIdx.x >> 6;
  const int bId  = blockIdx.x;
  const int g    = (bId & 7) * 2 + ((bId >> 3) & 1);
  const int m    = bId >> 4;

  const int fcol = lane & 15;                // batch row (fragments AND pointwise)
  const int kq   = lane >> 4;                // k-quarter / channel sub-index
  const int chq  = m * 16 + w * 4 + kq;      // this lane's pointwise channel
  const int bgl  = g * 16 + fcol;            // this lane's batch

  unsigned* fe_g = (unsigned*)(ws + OFF_FE) + g * 64;
  u16* h0s = (u16*)(ws + OFF_H0) + (size_t)g * 2 * 4096;
  u16* h1s = (u16*)(ws + OFF_H1) + (size_t)g * 2 * 4096;
  u16* f0s = (u16*)(ws + OFF_F0) + (size_t)g * 4096;
  u16* f1s = (u16*)(ws + OFF_F1) + (size_t)g * 4096;
  float* c0ws = (float*)(ws + OFF_C0);
  float* c1ws = (float*)(ws + OFF_C1);

  // weight fragments: wave w owns gate-cols n = 16w + fcol; row = (n&3)*H + m*16 + (n>>2)
  const int n    = 16 * w + fcol;
  const int grow = (n & 3) * HDIM + m * 16 + (n >> 2);
  short8 wh0[8], wi1[8], wh1[8];
#pragma unroll
  for (int kf = 0; kf < 8; kf++) {
    const int k0 = kf * 32 + kq * 8;
    wh0[kf] = ld_frag8(Whh0, grow, HDIM, k0, mode);
    wi1[kf] = ld_frag8(Wih1, grow, HDIM, k0, mode);
    wh1[kf] = ld_frag8(Whh1, grow, HDIM, k0, mode);
  }
  float wx[4], bb0[4], bb1[4];
#pragma unroll
  for (int gt = 0; gt < 4; gt++) {
    wx[gt]  = ld_scalar(Wih0, gt * HDIM + chq, mode);
    bb0[gt] = ld_scalar(b0,   gt * HDIM + chq, mode);
    bb1[gt] = ld_scalar(b1,   gt * HDIM + chq, mode);
  }
  float c0 = 0.f, c1 = 0.f, h0keep = 0.f;

  for (int t = 0; t <= S_LEN; t++) {
    const int pr = (t + 1) & 1, pw = t & 1;
    if (t >= 1) pollge(fe_g, (unsigned)t);
    short8 a0[8], a1[8];
    if (t >= 1) issue8(h0s + pr * 4096 + fcol * 256 + kq * 8, a0);
    if (t >= 2) issue8(h1s + pr * 4096 + fcol * 256 + kq * 8, a1);
    if (t >= 1) waitv0();

    f32x4 acc0 = {0.f, 0.f, 0.f, 0.f}, acc1 = {0.f, 0.f, 0.f, 0.f};
    if (t >= 1 && t < S_LEN) {
#pragma unroll
      for (int kf = 0; kf < 8; kf++) acc0 = mfma_bf16(wh0[kf], a0[kf], acc0);  // swapped
    }
    if (t >= 1) {
#pragma unroll
      for (int kf = 0; kf < 8; kf++) acc1 = mfma_bf16(wi1[kf], a0[kf], acc1);
      if (t >= 2) {
#pragma unroll
        for (int kf = 0; kf < 8; kf++) acc1 = mfma_bf16(wh1[kf], a1[kf], acc1);
      }
    }
    // direct pointwise: acc[i] = gate i of (chq, batch fcol)
    if (t < S_LEN) {
      const float x = ld_scalar(feat, (long)bgl * S_LEN + t, mode);
      const float gi = acc0[0] + x * wx[0] + bb0[0];
      const float gf = acc0[1] + x * wx[1] + bb0[1];
      const float gg = acc0[2] + x * wx[2] + bb0[2];
      const float go = acc0[3] + x * wx[3] + bb0[3];
      c0 = sigm(gf) * c0 + sigm(gi) * tanhf(gg);
      const float h0v = sigm(go) * tanhf(c0);
      h0keep = h0v;
      st16(h0s + pw * 4096 + fcol * 256 + chq, f2bf(h0v));
    }
    if (t >= 1) {
      const float gi = acc1[0] + bb1[0];
      const float gf = acc1[1] + bb1[1];
      const float gg = acc1[2] + bb1[2];
      const float go = acc1[3] + bb1[3];
      c1 = sigm(gf) * c1 + sigm(gi) * tanhf(gg);
      const float h1v = sigm(go) * tanhf(c1);
      st16(h1s + pw * 4096 + fcol * 256 + chq, f2bf(h1v));
      if (t == S_LEN) {                                 // write-once handoff slabs
        st16(f0s + fcol * 256 + chq, f2bf(h0keep));
        st16(f1s + fcol * 256 + chq, f2bf(h1v));
      }
    }
    publish(fe_g + m * 4 + w, (unsigned)(t + 1));
  }
  c0ws[(size_t)bgl * HDIM + chq] = c0;   // dec reads via kernel-boundary ordering
  c1ws[(size_t)bgl * HDIM + chq] = c1;
}

// ============================ decoder ============================
// Per-wave flag epochs: phase A of step s -> 3s+1, B -> 3s+2, C -> 3s+3.
// Phase A (s>0) polls >=3s (partial(s-1) + h0(s-1)); B polls >=3s+1; C >=3s+2.
// s=0 state from fin slabs + c0ws/c1ws (kernel-boundary ordered after enc).
__global__ void __launch_bounds__(256, 1)
dec_kernel(const void* __restrict__ Wih0, const void* __restrict__ Whh0, const void* __restrict__ b0,
           const void* __restrict__ Wih1, const void* __restrict__ Whh1, const void* __restrict__ b1,
           const void* __restrict__ W1, const void* __restrict__ b1h, const void* __restrict__ W2,
           const void* __restrict__ b2, char* __restrict__ ws, void* __restrict__ out) {
  const int mode = (int)*(const unsigned*)(ws + OFF_FLAG);
  const int tid  = threadIdx.x;
  const int lane = tid & 63;
  const int w    = tid >> 6;
  const int bId  = blockIdx.x;
  const int g    = (bId & 7) * 2 + ((bId >> 3) & 1);
  const int m    = bId >> 4;

  const int fcol = lane & 15;
  const int kq   = lane >> 4;
  const int chq  = m * 16 + w * 4 + kq;
  const int bgl  = g * 16 + fcol;

  unsigned* fd_g = (unsigned*)(ws + OFF_FD) + g * 64;
  u16* h0s = (u16*)(ws + OFF_H0) + (size_t)g * 2 * 4096;
  u16* h1s = (u16*)(ws + OFF_H1) + (size_t)g * 2 * 4096;
  u16* f0s = (u16*)(ws + OFF_F0) + (size_t)g * 4096;
  u16* f1s = (u16*)(ws + OFF_F1) + (size_t)g * 4096;
  float* partial = (float*)(ws + OFF_PART);
  float* c0ws = (float*)(ws + OFF_C0);
  float* c1ws = (float*)(ws + OFF_C1);

  __shared__ float part[4 * 256];
  __shared__ float redv[256];
  __shared__ float xacc[256];

  const int n    = 16 * w + fcol;
  const int grow = (n & 3) * HDIM + m * 16 + (n >> 2);
  short8 wh0[8], wi1[8], wh1[8], ww1[2];
#pragma unroll
  for (int kf = 0; kf < 8; kf++) {
    const int k0 = kf * 32 + kq * 8;
    wh0[kf] = ld_frag8(Whh0, grow, HDIM, k0, mode);
    wi1[kf] = ld_frag8(Wih1, grow, HDIM, k0, mode);
    wh1[kf] = ld_frag8(Whh1, grow, HDIM, k0, mode);
  }
#pragma unroll
  for (int kf2 = 0; kf2 < 2; kf2++) {
    const int k0 = w * 64 + kf2 * 32 + kq * 8;       // K-split of head GEMM across waves
    ww1[kf2] = ld_frag8(W1, m * 16 + fcol, HDIM, k0, mode);
  }
  float wx[4], bb0[4], bb1[4];
#pragma unroll
  for (int gt = 0; gt < 4; gt++) {
    wx[gt]  = ld_scalar(Wih0, gt * HDIM + chq, mode);
    bb0[gt] = ld_scalar(b0,   gt * HDIM + chq, mode);
    bb1[gt] = ld_scalar(b1,   gt * HDIM + chq, mode);
  }
  const int hb = tid & 15, hcl = tid >> 4;           // head reduce roles
  const int pm = tid >> 4, pbb = tid & 15;           // partial-read roles
  const float b1hv = ld_scalar(b1h, m * 16 + hcl, mode);
  const float w2v  = ld_scalar(W2,  m * 16 + hcl, mode);
  const float b2v  = ld_scalar(b2, 0, mode);

  float c0 = c0ws[(size_t)bgl * HDIM + chq];
  float c1 = c1ws[(size_t)bgl * HDIM + chq];

  for (int s = 0; s < T_LEN; s++) {
    const int ppr = (s - 1) & 1, pcur = s & 1;
    // ---------- phase A: gather pred(s-1), layer0 ----------
    float x = 0.f;
    short8 a0[8];
    if (s > 0) {
      pollge(fd_g, (unsigned)(3 * s));
      issue8(h0s + ppr * 4096 + fcol * 256 + kq * 8, a0);
      const float pv = ldf32(partial + (((size_t)ppr * 16 + g) * 16 + pm) * 16 + pbb);
      xacc[pbb * 16 + pm] = pv;
      __syncthreads();
#pragma unroll
      for (int j = 0; j < 16; j++) x += xacc[fcol * 16 + j];
      if (m == 0 && tid < 16)
        st_out(out, (size_t)(g * 16 + tid) * T_LEN + (s - 1), x, mode);
    } else {
      issue8(f0s + fcol * 256 + kq * 8, a0);
    }
    waitv0();
    {
      f32x4 acc = {0.f, 0.f, 0.f, 0.f};
#pragma unroll
      for (int kf = 0; kf < 8; kf++) acc = mfma_bf16(wh0[kf], a0[kf], acc);
      const float gi = acc[0] + x * wx[0] + bb0[0];
      const float gf = acc[1] + x * wx[1] + bb0[1];
      const float gg = acc[2] + x * wx[2] + bb0[2];
      const float go = acc[3] + x * wx[3] + bb0[3];
      c0 = sigm(gf) * c0 + sigm(gi) * tanhf(gg);
      const float h0v = sigm(go) * tanhf(c0);
      st16(h0s + pcur * 4096 + fcol * 256 + chq, f2bf(h0v));
    }
    publish(fd_g + m * 4 + w, (unsigned)(3 * s + 1));
    // ---------- phase B: layer1 ----------
    {
      pollge(fd_g, (unsigned)(3 * s + 1));
      short8 ay[8], a1[8];
      issue8(h0s + pcur * 4096 + fcol * 256 + kq * 8, ay);
      issue8(((s == 0) ? f1s : (h1s + ppr * 4096)) + fcol * 256 + kq * 8, a1);
      waitv0();
      f32x4 acc = {0.f, 0.f, 0.f, 0.f};
#pragma unroll
      for (int kf = 0; kf < 8; kf++) {
        acc = mfma_bf16(wi1[kf], ay[kf], acc);
        acc = mfma_bf16(wh1[kf], a1[kf], acc);
      }
      const float gi = acc[0] + bb1[0];
      const float gf = acc[1] + bb1[1];
      const float gg = acc[2] + bb1[2];
      const float go = acc[3] + bb1[3];
      c1 = sigm(gf) * c1 + sigm(gi) * tanhf(gg);
      const float h1v = sigm(go) * tanhf(c1);
      st16(h1s + pcur * 4096 + fcol * 256 + chq, f2bf(h1v));
    }
    publish(fd_g + m * 4 + w, (unsigned)(3 * s + 2));
    // ---------- phase C: head (Linear->ReLU->Linear), K-split across waves ----------
    {
      pollge(fd_g, (unsigned)(3 * s + 2));
      short8 ah[2];
      issue2(h1s + pcur * 4096 + fcol * 256 + w * 64 + kq * 8, ah);
      waitv0();
      f32x4 acc = {0.f, 0.f, 0.f, 0.f};
      acc = mfma_bf16(ww1[0], ah[0], acc);
      acc = mfma_bf16(ww1[1], ah[1], acc);
      // acc[i] = hidden[hch m*16 + 4kq+i][batch fcol] (K-slice w)
      *(f32x4*)&part[w * 256 + fcol * 16 + kq * 4] = acc;
      __syncthreads();
      float hid = part[0 * 256 + hb * 16 + hcl] + part[1 * 256 + hb * 16 + hcl]
                + part[2 * 256 + hb * 16 + hcl] + part[3 * 256 + hb * 16 + hcl] + b1hv;
      hid = fmaxf(hid, 0.f);
      redv[hcl * 16 + hb] = hid * w2v;
      __syncthreads();
      if (tid < 16) {
        float a = (m == 0) ? b2v : 0.f;
#pragma unroll
        for (int cc = 0; cc < 16; cc++) a += redv[cc * 16 + tid];
        stf32(partial + (((size_t)pcur * 16 + g) * 16 + m) * 16 + tid, a);
      }
    }
    publish(fd_g + m * 4 + w, (unsigned)(3 * s + 3));
  }
  // final output column: pred(T-1) from partials of step T-1 (parity 1)
  if (m == 0) {
    pollge(fd_g, (unsigned)(3 * T_LEN));
    const float pv = ldf32(partial + (((size_t)1 * 16 + g) * 16 + pm) * 16 + pbb);
    xacc[pbb * 16 + pm] = pv;
    __syncthreads();
    if (tid < 16) {
      float x = 0.f;
#pragma unroll
      for (int j = 0; j < 16; j++) x += xacc[tid * 16 + j];
      st_out(out, (size_t)(g * 16 + tid) * T_LEN + (T_LEN - 1), x, mode);
    }
  }
}

extern "C" void kernel_launch(void* const* d_in, const int* in_sizes, int n_in,
                              void* d_out, int out_size, void* d_ws, size_t ws_size,
                              hipStream_t stream) {
  char* ws = (char*)d_ws;
  // zero flags + partials every launch (replay-safe: epoch 0 == empty)
  hipMemsetAsync(ws, 0, ZERO_END, stream);
  detect_mode<<<1, 64, 0, stream>>>((const unsigned*)d_in[0], (unsigned*)(ws + OFF_FLAG));
  enc_kernel<<<256, 256, 0, stream>>>(d_in[0], d_in[1], d_in[2], d_in[3],
                                      d_in[4], d_in[5], d_in[6], ws);
  dec_kernel<<<256, 256, 0, stream>>>(d_in[7], d_in[8], d_in[9], d_in[10], d_in[11], d_in[12],
                                      d_in[13], d_in[14], d_in[15], d_in[16], ws, d_out);
}

// Round 7
// 4114.825 us; speedup vs baseline: 6.4533x; 2.0636x over previous
//
#include <hip/hip_runtime.h>

// Seq2Seq LSTM forecaster: H=256, B=256, S=672, T=96.
// Round 7: de-atomized control plane.
//   - r6 was bottlenecked by TCC atomic-unit serialization: 64 atomic flag stores +
//     1024 atomic flag loads per tick into 2 cache lines (~20-30cy each, serialized)
//     = ~9.6us/tick. Polling a monotonic epoch needs no atomicity.
//   - Flags: ONE per wg (16/group), padded to 32B sectors. Publish = per-wave
//     vmcnt(0) drain -> __syncthreads -> tid0 plain sc0 sc1 store.
//   - Poll: plain sc0 sc1 loads (normal read path, no atomic serialization),
//     lanes read the 16 wg-flags, __all(>= epoch).
//   - Data plane unchanged from r6: batched asm global_load/store sc0 sc1 (IC-coherent),
//     swapped MFMA (weights=A, h=B), zero-LDS encoder, 3-phase decoder.

#define S_LEN 672
#define T_LEN 96
#define HDIM  256
#define SPIN_MAX (1 << 14)

typedef short short8 __attribute__((ext_vector_type(8)));
typedef float f32x4  __attribute__((ext_vector_type(4)));
typedef unsigned short u16;

// ---- workspace layout (bytes) ----
#define OFF_FLAG 0                                  // dtype mode flag
#define OFF_FE   1024                               // enc flags: [16g][16wg] u32 @ 32B stride
#define OFF_FD   (OFF_FE + 16*16*32)                // dec flags: same shape
#define OFF_PART (OFF_FD + 16*16*32)                // f32 [2][16g][16m][16b]
#define ZERO_END (OFF_PART + 2*16*256*4)
#define OFF_H0   ZERO_END                           // u16 [16g][2][16b][256ch]
#define OFF_H1   (OFF_H0 + 16*2*4096*2)
#define OFF_F0   (OFF_H1 + 16*2*4096*2)             // u16 [16g][16b][256ch] h0 final
#define OFF_F1   (OFF_F0 + 16*4096*2)               // u16 [16g][16b][256ch] h1 final
#define OFF_C0   (OFF_F1 + 16*4096*2)               // f32 [256][256]
#define OFF_C1   (OFF_C0 + 256*256*4)

__device__ __forceinline__ unsigned short f2bf(float f) {
  unsigned u = __float_as_uint(f);
  u += 0x7FFFu + ((u >> 16) & 1u);
  return (unsigned short)(u >> 16);
}
__device__ __forceinline__ float bf2f(unsigned short s) {
  return __uint_as_float(((unsigned)s) << 16);
}
__device__ __forceinline__ float ld_scalar(const void* p, long idx, int mode) {
  if (mode) return bf2f(((const u16*)p)[idx]);
  return ((const float*)p)[idx];
}
__device__ __forceinline__ short8 ld_frag8(const void* p, long row, long ld, long k0, int mode) {
  if (mode) {
    return *(const short8*)((const u16*)p + row * ld + k0);
  } else {
    const float* f = (const float*)p + row * ld + k0;
    short8 r;
#pragma unroll
    for (int i = 0; i < 8; i++) r[i] = (short)f2bf(f[i]);
    return r;
  }
}
__device__ __forceinline__ void st_out(void* out, size_t idx, float v, int mode) {
  if (mode) ((u16*)out)[idx] = f2bf(v);
  else      ((float*)out)[idx] = v;
}
__device__ __forceinline__ float sigm(float x) { return 1.f / (1.f + __expf(-x)); }

__device__ __forceinline__ f32x4 mfma_bf16(short8 a, short8 b, f32x4 c) {
  return __builtin_amdgcn_mfma_f32_16x16x32_bf16(a, b, c, 0, 0, 0);
}

// ---- agent-coherent data plane (sc0 sc1 = coherence-point access) ----
__device__ __forceinline__ void issue8(const u16* base, short8* t) {
  asm volatile(
    "global_load_dwordx4 %0, %8, off sc0 sc1\n\t"
    "global_load_dwordx4 %1, %8, off offset:64 sc0 sc1\n\t"
    "global_load_dwordx4 %2, %8, off offset:128 sc0 sc1\n\t"
    "global_load_dwordx4 %3, %8, off offset:192 sc0 sc1\n\t"
    "global_load_dwordx4 %4, %8, off offset:256 sc0 sc1\n\t"
    "global_load_dwordx4 %5, %8, off offset:320 sc0 sc1\n\t"
    "global_load_dwordx4 %6, %8, off offset:384 sc0 sc1\n\t"
    "global_load_dwordx4 %7, %8, off offset:448 sc0 sc1"
    : "=&v"(t[0]), "=&v"(t[1]), "=&v"(t[2]), "=&v"(t[3]),
      "=&v"(t[4]), "=&v"(t[5]), "=&v"(t[6]), "=&v"(t[7])
    : "v"(base) : "memory");
}
__device__ __forceinline__ void issue2(const u16* base, short8* t) {
  asm volatile(
    "global_load_dwordx4 %0, %2, off sc0 sc1\n\t"
    "global_load_dwordx4 %1, %2, off offset:64 sc0 sc1"
    : "=&v"(t[0]), "=&v"(t[1]) : "v"(base) : "memory");
}
__device__ __forceinline__ void st16(u16* p, unsigned short v) {
  asm volatile("global_store_short %0, %1, off sc0 sc1"
               :: "v"(p), "v"((unsigned)v) : "memory");
}
__device__ __forceinline__ void stf32(float* p, float v) {
  asm volatile("global_store_dword %0, %1, off sc0 sc1"
               :: "v"(p), "v"(v) : "memory");
}
__device__ __forceinline__ float ldf32(const float* p) {
  float v;
  asm volatile("global_load_dword %0, %1, off sc0 sc1\n\ts_waitcnt vmcnt(0)"
               : "=&v"(v) : "v"(p) : "memory");
  __builtin_amdgcn_sched_barrier(0);
  return v;
}
__device__ __forceinline__ void waitv0() {
  asm volatile("s_waitcnt vmcnt(0)" ::: "memory");
  __builtin_amdgcn_sched_barrier(0);
}
__device__ __forceinline__ void waitv8() {
  asm volatile("s_waitcnt vmcnt(8)" ::: "memory");
  __builtin_amdgcn_sched_barrier(0);
}

// ---- control plane: plain sc0 sc1 epoch flags (no atomics, no serialization) ----
// flags base (u32*): group g -> + g*128; wg m's flag word at + m*8 (32B sector stride).
// Publish: each wave drains its stores to the coherence point, block-barrier so all
// four waves' data is globally visible, then tid0 plain-stores the epoch.
__device__ __forceinline__ void wg_publish(unsigned* fa, unsigned e) {
  asm volatile("s_waitcnt vmcnt(0)" ::: "memory");
  __syncthreads();
  if (threadIdx.x == 0)
    asm volatile("global_store_dword %0, %1, off sc0 sc1" :: "v"(fa), "v"(e) : "memory");
}
// All lanes poll the 16 wg-flags (lane&15 selects the flag, 4 lanes/sector broadcast).
__device__ __forceinline__ void pollge(const unsigned* flags, unsigned E) {
  const unsigned* addr = flags + (threadIdx.x & 15) * 8;
  int spin = 0;
  for (;;) {
    unsigned v;
    asm volatile("global_load_dword %0, %1, off sc0 sc1\n\ts_waitcnt vmcnt(0)"
                 : "=&v"(v) : "v"(addr) : "memory");
    if (__all(v >= E)) break;
    if (++spin > SPIN_MAX) break;
    __builtin_amdgcn_s_sleep(1);
  }
  __builtin_amdgcn_sched_barrier(0);
}

// ---- dtype detector ----
__global__ void detect_mode(const unsigned* __restrict__ feat, unsigned* __restrict__ flag) {
  const int t = threadIdx.x;
  int cnt = 0;
#pragma unroll
  for (int i = 0; i < 8; i++) {
    const unsigned wv = feat[t * 8 + i];
    const unsigned e = (wv >> 7) & 0xFFu;
    cnt += (e >= 100u && e <= 130u) ? 1 : 0;
  }
#pragma unroll
  for (int o = 32; o > 0; o >>= 1) cnt += __shfl_down(cnt, o, 64);
  if (t == 0) flag[0] = (cnt >= 256) ? 1u : 0u;
}

// ============================ encoder ============================
// Tick t (0..672): layer0 computes step t (t<672), layer1 computes step t-1 (t>=1).
// Per-wg flag after tick t = t+1 (covers all 4 waves' h0(t)/h1(t-1) stores, drained).
// Tick-t reads poll >= t. Slab parity: h(t) at t&1; tick-t reads at (t+1)&1.
// Two-generation safety: writer at t+2 polled >= t+2 => all tick-(t+1) readers done.
__global__ void __launch_bounds__(256, 1)
enc_kernel(const void* __restrict__ feat,
           const void* __restrict__ Wih0, const void* __restrict__ Whh0, const void* __restrict__ b0,
           const void* __restrict__ Wih1, const void* __restrict__ Whh1, const void* __restrict__ b1,
           char* __restrict__ ws) {
  const int mode = (int)*(const unsigned*)(ws + OFF_FLAG);
  const int lane = threadIdx.x & 63;
  const int w    = threadIdx.x >> 6;
  const int bId  = blockIdx.x;
  const int g    = (bId & 7) * 2 + ((bId >> 3) & 1);
  const int m    = bId >> 4;

  const int fcol = lane & 15;                // batch row (fragments AND pointwise)
  const int kq   = lane >> 4;                // k-quarter / channel sub-index
  const int chq  = m * 16 + w * 4 + kq;      // this lane's pointwise channel
  const int bgl  = g * 16 + fcol;            // this lane's batch

  unsigned* fe_g = (unsigned*)(ws + OFF_FE) + g * 128;
  u16* h0s = (u16*)(ws + OFF_H0) + (size_t)g * 2 * 4096;
  u16* h1s = (u16*)(ws + OFF_H1) + (size_t)g * 2 * 4096;
  u16* f0s = (u16*)(ws + OFF_F0) + (size_t)g * 4096;
  u16* f1s = (u16*)(ws + OFF_F1) + (size_t)g * 4096;
  float* c0ws = (float*)(ws + OFF_C0);
  float* c1ws = (float*)(ws + OFF_C1);

  // weight fragments: wave w owns gate-cols n = 16w + fcol; row = (n&3)*H + m*16 + (n>>2)
  const int n    = 16 * w + fcol;
  const int grow = (n & 3) * HDIM + m * 16 + (n >> 2);
  short8 wh0[8], wi1[8], wh1[8];
#pragma unroll
  for (int kf = 0; kf < 8; kf++) {
    const int k0 = kf * 32 + kq * 8;
    wh0[kf] = ld_frag8(Whh0, grow, HDIM, k0, mode);
    wi1[kf] = ld_frag8(Wih1, grow, HDIM, k0, mode);
    wh1[kf] = ld_frag8(Whh1, grow, HDIM, k0, mode);
  }
  float wx[4], bb0[4], bb1[4];
#pragma unroll
  for (int gt = 0; gt < 4; gt++) {
    wx[gt]  = ld_scalar(Wih0, gt * HDIM + chq, mode);
    bb0[gt] = ld_scalar(b0,   gt * HDIM + chq, mode);
    bb1[gt] = ld_scalar(b1,   gt * HDIM + chq, mode);
  }
  float c0 = 0.f, c1 = 0.f, h0keep = 0.f;

  for (int t = 0; t <= S_LEN; t++) {
    const int pr = (t + 1) & 1, pw = t & 1;
    if (t >= 1) pollge(fe_g, (unsigned)t);
    short8 a0[8], a1[8];
    if (t >= 1) issue8(h0s + pr * 4096 + fcol * 256 + kq * 8, a0);
    if (t >= 2) { issue8(h1s + pr * 4096 + fcol * 256 + kq * 8, a1); waitv8(); }
    else if (t == 1) waitv0();

    f32x4 acc0 = {0.f, 0.f, 0.f, 0.f}, acc1 = {0.f, 0.f, 0.f, 0.f};
    if (t >= 1 && t < S_LEN) {
#pragma unroll
      for (int kf = 0; kf < 8; kf++) acc0 = mfma_bf16(wh0[kf], a0[kf], acc0);  // swapped
    }
    if (t >= 1) {
#pragma unroll
      for (int kf = 0; kf < 8; kf++) acc1 = mfma_bf16(wi1[kf], a0[kf], acc1);
      if (t >= 2) {
        waitv0();
#pragma unroll
        for (int kf = 0; kf < 8; kf++) acc1 = mfma_bf16(wh1[kf], a1[kf], acc1);
      }
    }
    // direct pointwise: acc[i] = gate i of (chq, batch fcol)
    if (t < S_LEN) {
      const float x = ld_scalar(feat, (long)bgl * S_LEN + t, mode);
      const float gi = acc0[0] + x * wx[0] + bb0[0];
      const float gf = acc0[1] + x * wx[1] + bb0[1];
      const float gg = acc0[2] + x * wx[2] + bb0[2];
      const float go = acc0[3] + x * wx[3] + bb0[3];
      c0 = sigm(gf) * c0 + sigm(gi) * tanhf(gg);
      const float h0v = sigm(go) * tanhf(c0);
      h0keep = h0v;
      st16(h0s + pw * 4096 + fcol * 256 + chq, f2bf(h0v));
    }
    if (t >= 1) {
      const float gi = acc1[0] + bb1[0];
      const float gf = acc1[1] + bb1[1];
      const float gg = acc1[2] + bb1[2];
      const float go = acc1[3] + bb1[3];
      c1 = sigm(gf) * c1 + sigm(gi) * tanhf(gg);
      const float h1v = sigm(go) * tanhf(c1);
      st16(h1s + pw * 4096 + fcol * 256 + chq, f2bf(h1v));
      if (t == S_LEN) {                                 // write-once handoff slabs
        st16(f0s + fcol * 256 + chq, f2bf(h0keep));
        st16(f1s + fcol * 256 + chq, f2bf(h1v));
      }
    }
    wg_publish(fe_g + m * 8, (unsigned)(t + 1));
  }
  c0ws[(size_t)bgl * HDIM + chq] = c0;   // dec reads via kernel-boundary ordering
  c1ws[(size_t)bgl * HDIM + chq] = c1;
}

// ============================ decoder ============================
// Per-wg flag epochs: phase A of step s -> 3s+1, B -> 3s+2, C -> 3s+3.
// Phase A (s>0) polls >=3s (partial(s-1) + h0(s-1)); B polls >=3s+1; C >=3s+2.
// s=0 state from fin slabs + c0ws/c1ws (kernel-boundary ordered after enc).
__global__ void __launch_bounds__(256, 1)
dec_kernel(const void* __restrict__ Wih0, const void* __restrict__ Whh0, const void* __restrict__ b0,
           const void* __restrict__ Wih1, const void* __restrict__ Whh1, const void* __restrict__ b1,
           const void* __restrict__ W1, const void* __restrict__ b1h, const void* __restrict__ W2,
           const void* __restrict__ b2, char* __restrict__ ws, void* __restrict__ out) {
  const int mode = (int)*(const unsigned*)(ws + OFF_FLAG);
  const int tid  = threadIdx.x;
  const int lane = tid & 63;
  const int w    = tid >> 6;
  const int bId  = blockIdx.x;
  const int g    = (bId & 7) * 2 + ((bId >> 3) & 1);
  const int m    = bId >> 4;

  const int fcol = lane & 15;
  const int kq   = lane >> 4;
  const int chq  = m * 16 + w * 4 + kq;
  const int bgl  = g * 16 + fcol;

  unsigned* fd_g = (unsigned*)(ws + OFF_FD) + g * 128;
  u16* h0s = (u16*)(ws + OFF_H0) + (size_t)g * 2 * 4096;
  u16* h1s = (u16*)(ws + OFF_H1) + (size_t)g * 2 * 4096;
  u16* f0s = (u16*)(ws + OFF_F0) + (size_t)g * 4096;
  u16* f1s = (u16*)(ws + OFF_F1) + (size_t)g * 4096;
  float* partial = (float*)(ws + OFF_PART);
  float* c0ws = (float*)(ws + OFF_C0);
  float* c1ws = (float*)(ws + OFF_C1);

  __shared__ float part[4 * 256];
  __shared__ float redv[256];
  __shared__ float xacc[256];

  const int n    = 16 * w + fcol;
  const int grow = (n & 3) * HDIM + m * 16 + (n >> 2);
  short8 wh0[8], wi1[8], wh1[8], ww1[2];
#pragma unroll
  for (int kf = 0; kf < 8; kf++) {
    const int k0 = kf * 32 + kq * 8;
    wh0[kf] = ld_frag8(Whh0, grow, HDIM, k0, mode);
    wi1[kf] = ld_frag8(Wih1, grow, HDIM, k0, mode);
    wh1[kf] = ld_frag8(Whh1, grow, HDIM, k0, mode);
  }
#pragma unroll
  for (int kf2 = 0; kf2 < 2; kf2++) {
    const int k0 = w * 64 + kf2 * 32 + kq * 8;       // K-split of head GEMM across waves
    ww1[kf2] = ld_frag8(W1, m * 16 + fcol, HDIM, k0, mode);
  }
  float wx[4], bb0[4], bb1[4];
#pragma unroll
  for (int gt = 0; gt < 4; gt++) {
    wx[gt]  = ld_scalar(Wih0, gt * HDIM + chq, mode);
    bb0[gt] = ld_scalar(b0,   gt * HDIM + chq, mode);
    bb1[gt] = ld_scalar(b1,   gt * HDIM + chq, mode);
  }
  const int hb = tid & 15, hcl = tid >> 4;           // head reduce roles
  const int pm = tid >> 4, pbb = tid & 15;           // partial-read roles
  const float b1hv = ld_scalar(b1h, m * 16 + hcl, mode);
  const float w2v  = ld_scalar(W2,  m * 16 + hcl, mode);
  const float b2v  = ld_scalar(b2, 0, mode);

  float c0 = c0ws[(size_t)bgl * HDIM + chq];
  float c1 = c1ws[(size_t)bgl * HDIM + chq];

  for (int s = 0; s < T_LEN; s++) {
    const int ppr = (s - 1) & 1, pcur = s & 1;
    // ---------- phase A: gather pred(s-1), layer0 ----------
    float x = 0.f;
    short8 a0[8];
    if (s > 0) {
      pollge(fd_g, (unsigned)(3 * s));
      issue8(h0s + ppr * 4096 + fcol * 256 + kq * 8, a0);
      const float pv = ldf32(partial + (((size_t)ppr * 16 + g) * 16 + pm) * 16 + pbb);
      xacc[pbb * 16 + pm] = pv;
      __syncthreads();
#pragma unroll
      for (int j = 0; j < 16; j++) x += xacc[fcol * 16 + j];
      if (m == 0 && tid < 16)
        st_out(out, (size_t)(g * 16 + tid) * T_LEN + (s - 1), x, mode);
    } else {
      issue8(f0s + fcol * 256 + kq * 8, a0);
    }
    waitv0();
    {
      f32x4 acc = {0.f, 0.f, 0.f, 0.f};
#pragma unroll
      for (int kf = 0; kf < 8; kf++) acc = mfma_bf16(wh0[kf], a0[kf], acc);
      const float gi = acc[0] + x * wx[0] + bb0[0];
      const float gf = acc[1] + x * wx[1] + bb0[1];
      const float gg = acc[2] + x * wx[2] + bb0[2];
      const float go = acc[3] + x * wx[3] + bb0[3];
      c0 = sigm(gf) * c0 + sigm(gi) * tanhf(gg);
      const float h0v = sigm(go) * tanhf(c0);
      st16(h0s + pcur * 4096 + fcol * 256 + chq, f2bf(h0v));
    }
    wg_publish(fd_g + m * 8, (unsigned)(3 * s + 1));
    // ---------- phase B: layer1 ----------
    {
      pollge(fd_g, (unsigned)(3 * s + 1));
      short8 ay[8], a1[8];
      issue8(h0s + pcur * 4096 + fcol * 256 + kq * 8, ay);
      issue8(((s == 0) ? f1s : (h1s + ppr * 4096)) + fcol * 256 + kq * 8, a1);
      waitv8();
      f32x4 acc = {0.f, 0.f, 0.f, 0.f};
#pragma unroll
      for (int kf = 0; kf < 8; kf++) acc = mfma_bf16(wi1[kf], ay[kf], acc);
      waitv0();
#pragma unroll
      for (int kf = 0; kf < 8; kf++) acc = mfma_bf16(wh1[kf], a1[kf], acc);
      const float gi = acc[0] + bb1[0];
      const float gf = acc[1] + bb1[1];
      const float gg = acc[2] + bb1[2];
      const float go = acc[3] + bb1[3];
      c1 = sigm(gf) * c1 + sigm(gi) * tanhf(gg);
      const float h1v = sigm(go) * tanhf(c1);
      st16(h1s + pcur * 4096 + fcol * 256 + chq, f2bf(h1v));
    }
    wg_publish(fd_g + m * 8, (unsigned)(3 * s + 2));
    // ---------- phase C: head (Linear->ReLU->Linear), K-split across waves ----------
    {
      pollge(fd_g, (unsigned)(3 * s + 2));
      short8 ah[2];
      issue2(h1s + pcur * 4096 + fcol * 256 + w * 64 + kq * 8, ah);
      waitv0();
      f32x4 acc = {0.f, 0.f, 0.f, 0.f};
      acc = mfma_bf16(ww1[0], ah[0], acc);
      acc = mfma_bf16(ww1[1], ah[1], acc);
      // acc[i] = hidden[hch m*16 + 4kq+i][batch fcol] (K-slice w)
      *(f32x4*)&part[w * 256 + fcol * 16 + kq * 4] = acc;
      __syncthreads();
      float hid = part[0 * 256 + hb * 16 + hcl] + part[1 * 256 + hb * 16 + hcl]
                + part[2 * 256 + hb * 16 + hcl] + part[3 * 256 + hb * 16 + hcl] + b1hv;
      hid = fmaxf(hid, 0.f);
      redv[hcl * 16 + hb] = hid * w2v;
      __syncthreads();
      if (tid < 16) {
        float a = (m == 0) ? b2v : 0.f;
#pragma unroll
        for (int cc = 0; cc < 16; cc++) a += redv[cc * 16 + tid];
        stf32(partial + (((size_t)pcur * 16 + g) * 16 + m) * 16 + tid, a);
      }
    }
    wg_publish(fd_g + m * 8, (unsigned)(3 * s + 3));
  }
  // final output column: pred(T-1) from partials of step T-1 (parity 1)
  if (m == 0) {
    pollge(fd_g, (unsigned)(3 * T_LEN));
    const float pv = ldf32(partial + (((size_t)1 * 16 + g) * 16 + pm) * 16 + pbb);
    xacc[pbb * 16 + pm] = pv;
    __syncthreads();
    if (tid < 16) {
      float x = 0.f;
#pragma unroll
      for (int j = 0; j < 16; j++) x += xacc[tid * 16 + j];
      st_out(out, (size_t)(g * 16 + tid) * T_LEN + (T_LEN - 1), x, mode);
    }
  }
}

extern "C" void kernel_launch(void* const* d_in, const int* in_sizes, int n_in,
                              void* d_out, int out_size, void* d_ws, size_t ws_size,
                              hipStream_t stream) {
  char* ws = (char*)d_ws;
  // zero flags + partials every launch (replay-safe: epoch 0 == empty)
  hipMemsetAsync(ws, 0, ZERO_END, stream);
  detect_mode<<<1, 64, 0, stream>>>((const unsigned*)d_in[0], (unsigned*)(ws + OFF_FLAG));
  enc_kernel<<<256, 256, 0, stream>>>(d_in[0], d_in[1], d_in[2], d_in[3],
                                      d_in[4], d_in[5], d_in[6], ws);
  dec_kernel<<<256, 256, 0, stream>>>(d_in[7], d_in[8], d_in[9], d_in[10], d_in[11], d_in[12],
                                      d_in[13], d_in[14], d_in[15], d_in[16], ws, d_out);
}